// Round 12
// baseline (75.166 us; speedup 1.0000x reference)
//
#include <hip/hip_runtime.h>
#include <hip/hip_fp16.h>
#include <stdint.h>

#define B_ 2
#define F_ 2
#define C_ 128
#define D_ 96
#define H_ 48
#define W_ 128
#define HW_ (H_*W_)
#define EPS_ 1e-7f

typedef _Float16 f16x2 __attribute__((ext_vector_type(2)));
union U32H2 { unsigned u; f16x2 h; };

static __device__ __forceinline__ f16x2 asH2(unsigned u){ U32H2 t; t.u=u; return t.h; }
static __device__ __forceinline__ f16x2 habs2(f16x2 x){ U32H2 t; t.h=x; t.u&=0x7fff7fffu; return t.h; }

#if __has_builtin(__builtin_amdgcn_fdot2)
static __device__ __forceinline__ float dot2acc(f16x2 d, float acc){
    const f16x2 one = {(_Float16)1.0f, (_Float16)1.0f};
    return __builtin_amdgcn_fdot2(d, one, acc, false);
}
#else
static __device__ __forceinline__ float dot2acc(f16x2 d, float acc){ return acc + (float)d[0] + (float)d[1]; }
#endif

// 4-tap weighted sum with -cur folded into the innermost FMA
static __device__ __forceinline__ f16x2 bilin4(f16x2 ta, f16x2 tb, f16x2 tc, f16x2 td,
                                               f16x2 w00, f16x2 w01, f16x2 w10, f16x2 w11,
                                               f16x2 nc){
    f16x2 s = __builtin_elementwise_fma(td, w11, nc);
    s = __builtin_elementwise_fma(tc, w10, s);
    s = __builtin_elementwise_fma(tb, w01, s);
    s = __builtin_elementwise_fma(ta, w00, s);
    return s;
}

// butterfly add within 16-lane group via DPP (VALU pipe, no DS)
static __device__ __forceinline__ float dppadd(float x, const int ctrl){
    int p;
    switch (ctrl){
    case 0: p = __builtin_amdgcn_update_dpp(0, __float_as_int(x), 0xB1, 0xf, 0xf, true); break; // xor1
    case 1: p = __builtin_amdgcn_update_dpp(0, __float_as_int(x), 0x4E, 0xf, 0xf, true); break; // xor2
    case 2: p = __builtin_amdgcn_update_dpp(0, __float_as_int(x), 0x141, 0xf, 0xf, true); break; // xor4
    default: p = __builtin_amdgcn_update_dpp(0, __float_as_int(x), 0x140, 0xf, 0xf, true); break; // xor8
    }
    return x + __int_as_float(p);
}

__device__ __forceinline__ float depth_bin(int d){
    return (float)(0.1 + (double)d * (19.9 / 95.0));
}

// transpose + f32->f16: src [nslice][C][HW] f32 -> dst [nslice][HW][C] f16
__global__ void transpose_kernel(const float* __restrict__ src,
                                 _Float16* __restrict__ dst){
    __shared__ float tile[32][33];
    const int tx = threadIdx.x & 31, ty = threadIdx.x >> 5;
    const int nc = C_ / 32;     // 4
    const int np = HW_ / 32;    // 192
    int bid = blockIdx.x;
    int p0 = (bid % np) * 32;
    int c0 = ((bid / np) % nc) * 32;
    int s  = bid / (np * nc);
    const float* sp = src + (size_t)s * C_ * HW_;
    _Float16* dp = dst + (size_t)s * HW_ * C_;
#pragma unroll
    for (int j = 0; j < 4; ++j){
        int c = c0 + ty + j * 8;
        tile[ty + j * 8][tx] = sp[(size_t)c * HW_ + p0 + tx];
    }
    __syncthreads();
#pragma unroll
    for (int j = 0; j < 4; ++j){
        int p = p0 + ty + j * 8;
        dp[(size_t)p * C_ + c0 + tx] = (_Float16)tile[tx][ty + j * 8];
    }
}

// one wave per output pixel. 64 lanes = 4 groups x 16 lanes. Group g walks a
// CONTIGUOUS depth run: logical slot = (g>>1)*96 + (g&1)*48 + sq, sq=0..47
// (f = g>>1, d = (g&1)*48+sq). Storage layout meta[sq*4+g] keeps the 4 groups'
// broadcast ds_read_b128 conflict-free. Because the projected tap quad moves
// by ~1.5/d^2 px per depth step, most consecutive sq share the SAME quad:
// tap loads are guarded by (m.x != prevA) and tap registers retained —
// exec-masked loads fetch bytes only for groups whose quad changed (exact
// skip: same address => same data). R11 confirmed: 88.2 -> 67us.
// Config history: (256,8)+u4 spill storm; (256,4)+u4 = R8 best; (256,6)+u2
// regressed (MLP loss); R12: (256,6)+u4 now that VGPR=44 (budget 85, no
// spill expected) to lift occupancy 37% -> 50-60%. WRITE ~19MB = no-spill.
__global__ __launch_bounds__(256, 6)
void cost_tr_kernel(const float* __restrict__ poses,
                    const float* __restrict__ Kmat,
                    const float* __restrict__ invKm,
                    const _Float16* __restrict__ LT,
                    const _Float16* __restrict__ CT,
                    float* __restrict__ out_cost,
                    float* __restrict__ out_missing)
{
    __shared__ __align__(16) uint4 meta[4][192];   // 12288 B, storage slot ss = sq*4+g
    __shared__ float vals[4][256];                 // logical slot f*96+d (192 real + 64 scratch)

    const int wid  = threadIdx.x >> 6;
    const int lane = threadIdx.x & 63;
    const int pg   = blockIdx.x * 4 + wid;
    const int b    = pg / HW_;
    const int pix  = pg % HW_;
    const int h    = pix / W_;
    const int w    = pix % W_;
    const size_t ob = (size_t)b * D_ * HW_ + pix;

    // border fast path: whole column is cost=0, missing=1
    if (h < 2 || h > H_-3 || w < 2 || w > W_-3){
        out_cost[ob + (size_t)lane * HW_] = 0.f;
        out_missing[ob + (size_t)lane * HW_] = 1.f;
        if (lane < 32){
            out_cost[ob + (size_t)(64+lane) * HW_] = 0.f;
            out_missing[ob + (size_t)(64+lane) * HW_] = 1.f;
        }
        return;
    }

    // ---- projection setup for both frames (wave-uniform) ----
    float Qx[2], Qy[2], Qz[2], Tx[2], Ty[2], Tz[2], Vf[2];
    {
        const float* iK = invKm + b*16;
        const float u = (float)w, v = (float)h;
        const float dirx = iK[0]*u + iK[1]*v + iK[2];
        const float diry = iK[4]*u + iK[5]*v + iK[6];
        const float dirz = iK[8]*u + iK[9]*v + iK[10];
        const float* Kb = Kmat + b*16;
#pragma unroll
        for (int f = 0; f < 2; ++f){
            const float* ps = poses + ((size_t)b*F_ + f)*16;
            float psum = 0.f;
#pragma unroll
            for (int i = 0; i < 16; ++i) psum += ps[i];
            Vf[f] = (psum != 0.f) ? 1.f : 0.f;
            float P[3][4];
#pragma unroll
            for (int i = 0; i < 3; ++i)
#pragma unroll
                for (int j = 0; j < 4; ++j)
                    P[i][j] = Kb[i*4+0]*ps[j]    + Kb[i*4+1]*ps[4+j]
                            + Kb[i*4+2]*ps[8+j]  + Kb[i*4+3]*ps[12+j];
            Qx[f] = P[0][0]*dirx + P[0][1]*diry + P[0][2]*dirz;
            Qy[f] = P[1][0]*dirx + P[1][1]*diry + P[1][2]*dirz;
            Qz[f] = P[2][0]*dirx + P[2][1]*diry + P[2][2]*dirz;
            Tx[f] = P[0][3]; Ty[f] = P[1][3]; Tz[f] = P[2][3];
        }
    }

    // ---- meta build: lane-parallel over storage slots ss = sq*4 + g ----
#pragma unroll
    for (int g3 = 0; g3 < 3; ++g3){
        int ss = g3*64 + lane;
        int g  = ss & 3;
        int sq = ss >> 2;
        int f  = g >> 1;
        int d  = (g & 1)*48 + sq;
        float dv = depth_bin(d);
        float qx = f ? Qx[1] : Qx[0];
        float qy = f ? Qy[1] : Qy[0];
        float qz = f ? Qz[1] : Qz[0];
        float tx = f ? Tx[1] : Tx[0];
        float ty = f ? Ty[1] : Ty[0];
        float tz = f ? Tz[1] : Tz[0];
        float vfl = f ? Vf[1] : Vf[0];
        float cz = qz*dv + tz + EPS_;
        float x = (qx*dv + tx) / cz;
        float y = (qy*dv + ty) / cz;
        // edge => strictly interior => no clamping/validity needed;
        // non-edge slots contribute exactly 0 (mask word in .w).
        bool edge = (x >= 2.f) && (x <= (float)(W_-2)) &&
                    (y >= 2.f) && (y <= (float)(H_-2)) && (vfl != 0.f);
        float x0f = floorf(x), y0f = floorf(y);
        float wx1 = x - x0f, wy1 = y - y0f;
        float wx0 = 1.f - wx1, wy0 = 1.f - wy1;
        float xc = fminf(fmaxf(x0f, 0.f), (float)(W_-1));
        float yc = fminf(fmaxf(y0f, 0.f), (float)(H_-1));
        int ix0 = (int)xc, iy0 = (int)yc;
        int sb = (b*F_ + f) * HW_;
        unsigned mA = (unsigned)(sb + iy0*W_ + ix0) << 8;   // clean byte address
        U32H2 t0, t1;
        t0.h[0] = (_Float16)(wy0*wx0); t0.h[1] = (_Float16)(wy0*wx1);
        t1.h[0] = (_Float16)(wy1*wx0); t1.h[1] = (_Float16)(wy1*wx1);
        meta[wid][ss] = make_uint4(mA, t0.u, t1.u, edge ? 0xffffffffu : 0u);
    }

    // ---- cur channels for this lane: (lane&15)*8 .. +8 (negated for FMA fold) ----
    const char* CTc = (const char*)CT;
    const char* LTc = (const char*)LT;
    const unsigned chanoff = (unsigned)((lane & 15) * 16);
    const int grp = lane >> 4;
    const uint4 cu = *(const uint4*)(CTc + (size_t)(b*HW_ + pix) * (C_*2) + chanoff);
    const f16x2 nc0 = -asH2(cu.x), nc1 = -asH2(cu.y), nc2 = -asH2(cu.z), nc3 = -asH2(cu.w);

    // vals write address: winner lane (lane&15)==0 writes LOGICAL slot, rest scratch
    const bool winner = ((lane & 15) == 0);
    const unsigned logbase = (unsigned)(((grp >> 1)*96 + (grp & 1)*48) * 4);
    unsigned waddr = winner ? logbase : (unsigned)((192 + lane) * 4);
    const unsigned wstep = winner ? 4u : 0u;
    char* valsbase = (char*)&vals[wid][0];

    const uint4* metabase = &meta[wid][grp];

    unsigned prevA = 0xffffffffu;          // sentinel: mA always has low 8 bits 0
    uint4 ta = make_uint4(0,0,0,0), tb = ta, tc = ta, td = ta;

#pragma unroll 4
    for (int sq = 0; sq < 48; ++sq){
        uint4 m = metabase[sq*4];          // ds_read_b128, broadcast x16
        if (m.x != prevA){                 // group-uniform; exec-masked loads
            const char* p0 = LTc + (m.x + chanoff);
            ta = *(const uint4*)(p0);
            tb = *(const uint4*)(p0 + 256);
            tc = *(const uint4*)(p0 + 256*W_);
            td = *(const uint4*)(p0 + 256*W_ + 256);
        }
        prevA = m.x;
        f16x2 hA = asH2(m.y), hB = asH2(m.z);
        f16x2 w00 = {hA[0],hA[0]}, w01 = {hA[1],hA[1]};
        f16x2 w10 = {hB[0],hB[0]}, w11 = {hB[1],hB[1]};
        f16x2 s0 = bilin4(asH2(ta.x), asH2(tb.x), asH2(tc.x), asH2(td.x), w00,w01,w10,w11, nc0);
        f16x2 s1 = bilin4(asH2(ta.y), asH2(tb.y), asH2(tc.y), asH2(td.y), w00,w01,w10,w11, nc1);
        f16x2 s2 = bilin4(asH2(ta.z), asH2(tb.z), asH2(tc.z), asH2(td.z), w00,w01,w10,w11, nc2);
        f16x2 s3 = bilin4(asH2(ta.w), asH2(tb.w), asH2(tc.w), asH2(td.w), w00,w01,w10,w11, nc3);
        float part = dot2acc(habs2(s0), 0.f);
        part = dot2acc(habs2(s1), part);
        part = dot2acc(habs2(s2), part);
        part = dot2acc(habs2(s3), part);
        part = __uint_as_float(__float_as_uint(part) & m.w);   // precomputed edge mask
        part = dppadd(part, 0);
        part = dppadd(part, 1);
        part = dppadd(part, 2);
        part = dppadd(part, 3);
        *(float*)(valsbase + waddr) = part;
        waddr += wstep;
    }

    // ---- epilogue: pair df0/df1, divide, max-fill, store (vals logical layout) ----
    float v0 = vals[wid][lane];
    float v1 = vals[wid][64 + lane];
    float v2 = vals[wid][128 + lane];
    const float invc = 1.0f / C_;

    float sent = (lane < 32) ? v2 : v1;
    float df0_1 = v0 * invc;
    float df1_1 = __shfl_xor(sent, 32) * invc;
    float cnt1 = (df0_1 > 0.f ? 1.f : 0.f) + (df1_1 > 0.f ? 1.f : 0.f);
    float val1 = (df0_1 + df1_1) / (cnt1 + EPS_);

    float df0_2 = v1 * invc;
    float df1_2 = __shfl_xor(v2, 32) * invc;
    float cnt2 = (df0_2 > 0.f ? 1.f : 0.f) + (df1_2 > 0.f ? 1.f : 0.f);
    float val2 = (df0_2 + df1_2) / (cnt2 + EPS_);

    float vmax = fmaxf(val1, (lane < 32) ? val2 : 0.f);
#pragma unroll
    for (int mm = 1; mm < 64; mm <<= 1)
        vmax = fmaxf(vmax, __shfl_xor(vmax, mm));

    {
        size_t o = ob + (size_t)lane * HW_;
        out_cost[o]    = (val1 == 0.f) ? vmax : val1;
        out_missing[o] = (val1 == 0.f) ? 1.f : 0.f;
    }
    if (lane < 32){
        size_t o = ob + (size_t)(64 + lane) * HW_;
        out_cost[o]    = (val2 == 0.f) ? vmax : val2;
        out_missing[o] = (val2 == 0.f) ? 1.f : 0.f;
    }
}

// naive correct fallback (one thread per pixel column) — only runs if ws too small
__global__ void cost_naive_kernel(const float* __restrict__ cur,
                                  const float* __restrict__ look,
                                  const float* __restrict__ poses,
                                  const float* __restrict__ Kmat,
                                  const float* __restrict__ invKm,
                                  float* __restrict__ out_cost,
                                  float* __restrict__ out_missing)
{
    int t = blockIdx.x * blockDim.x + threadIdx.x;
    if (t >= B_*HW_) return;
    int b = t / HW_, pix = t % HW_;
    int h = pix / W_, w = pix % W_;
    size_t ob = (size_t)b * D_ * HW_ + pix;
    bool border = (h >= 2 && h <= H_-3 && w >= 2 && w <= W_-3);
    const float* iK = invKm + b*16;
    float u = (float)w, v = (float)h;
    float dirx = iK[0]*u + iK[1]*v + iK[2];
    float diry = iK[4]*u + iK[5]*v + iK[6];
    float dirz = iK[8]*u + iK[9]*v + iK[10];
    const float* Kb = Kmat + b*16;
    float vmax = 0.f;
    for (int d = 0; d < D_; ++d){
        float dfs[2];
        for (int f = 0; f < 2; ++f){
            const float* ps = poses + ((size_t)b*F_ + f)*16;
            float psum = 0.f;
            for (int i = 0; i < 16; ++i) psum += ps[i];
            float vfl = (psum != 0.f) ? 1.f : 0.f;
            float P[3][4];
            for (int i = 0; i < 3; ++i)
                for (int j = 0; j < 4; ++j)
                    P[i][j] = Kb[i*4+0]*ps[j] + Kb[i*4+1]*ps[4+j]
                            + Kb[i*4+2]*ps[8+j] + Kb[i*4+3]*ps[12+j];
            float qx = P[0][0]*dirx + P[0][1]*diry + P[0][2]*dirz;
            float qy = P[1][0]*dirx + P[1][1]*diry + P[1][2]*dirz;
            float qz = P[2][0]*dirx + P[2][1]*diry + P[2][2]*dirz;
            float dv = depth_bin(d);
            float cz = qz*dv + P[2][3] + EPS_;
            float x = (qx*dv + P[0][3]) / cz;
            float y = (qy*dv + P[1][3]) / cz;
            bool edge = border && (x >= 2.f) && (x <= (float)(W_-2)) &&
                        (y >= 2.f) && (y <= (float)(H_-2)) && (vfl != 0.f);
            float part = 0.f;
            if (edge){
                float x0f = floorf(x), y0f = floorf(y);
                float wx1 = x - x0f, wy1 = y - y0f;
                float wx0 = 1.f - wx1, wy0 = 1.f - wy1;
                int ix0 = (int)x0f, iy0 = (int)y0f;
                const float* lb = look + (size_t)(b*F_+f) * C_ * HW_;
                const float* cb = cur + (size_t)b * C_ * HW_ + pix;
                int o00 = iy0*W_ + ix0;
                for (int c = 0; c < C_; ++c){
                    const float* lc = lb + (size_t)c * HW_;
                    float wv = wy0*wx0*lc[o00] + wy0*wx1*lc[o00+1]
                             + wy1*wx0*lc[o00+W_] + wy1*wx1*lc[o00+W_+1];
                    part += fabsf(wv - cb[(size_t)c * HW_]);
                }
                part *= (1.0f/C_);
            }
            dfs[f] = part;
        }
        float cnt = (dfs[0] > 0.f ? 1.f : 0.f) + (dfs[1] > 0.f ? 1.f : 0.f);
        float val = (dfs[0] + dfs[1]) / (cnt + EPS_);
        out_cost[ob + (size_t)d * HW_] = val;
        vmax = fmaxf(vmax, val);
    }
    for (int d = 0; d < D_; ++d){
        float vv = out_cost[ob + (size_t)d * HW_];
        out_missing[ob + (size_t)d * HW_] = (vv == 0.f) ? 1.f : 0.f;
        if (vv == 0.f) out_cost[ob + (size_t)d * HW_] = vmax;
    }
}

extern "C" void kernel_launch(void* const* d_in, const int* in_sizes, int n_in,
                              void* d_out, int out_size, void* d_ws, size_t ws_size,
                              hipStream_t stream){
    const float* cur   = (const float*)d_in[0];
    const float* look  = (const float*)d_in[1];
    const float* poses = (const float*)d_in[2];
    const float* Kmat  = (const float*)d_in[3];
    const float* invKm = (const float*)d_in[4];
    float* cost    = (float*)d_out;
    float* missing = cost + (size_t)B_ * D_ * HW_;

    const size_t ltBytes = (size_t)B_ * F_ * HW_ * C_ * 2;
    const size_t ctBytes = (size_t)B_ * HW_ * C_ * 2;
    const bool useTR = (ws_size >= ltBytes + ctBytes);

    if (useTR){
        _Float16* LT = (_Float16*)d_ws;
        _Float16* CT = (_Float16*)((char*)d_ws + ltBytes);
        transpose_kernel<<<(B_*F_)*(C_/32)*(HW_/32), 256, 0, stream>>>(look, LT);
        transpose_kernel<<<B_*(C_/32)*(HW_/32), 256, 0, stream>>>(cur, CT);
        cost_tr_kernel<<<(B_*HW_)/4, 256, 0, stream>>>(poses, Kmat, invKm,
                                                       LT, CT, cost, missing);
    } else {
        cost_naive_kernel<<<(B_*HW_ + 255)/256, 256, 0, stream>>>(
            cur, look, poses, Kmat, invKm, cost, missing);
    }
}

// Round 13
// 74.455 us; speedup vs baseline: 1.0095x; 1.0095x over previous
//
#include <hip/hip_runtime.h>
#include <hip/hip_fp16.h>
#include <stdint.h>

#define B_ 2
#define F_ 2
#define C_ 128
#define D_ 96
#define H_ 48
#define W_ 128
#define HW_ (H_*W_)
#define EPS_ 1e-7f

typedef _Float16 f16x2 __attribute__((ext_vector_type(2)));
union U32H2 { unsigned u; f16x2 h; };

static __device__ __forceinline__ f16x2 asH2(unsigned u){ U32H2 t; t.u=u; return t.h; }
static __device__ __forceinline__ f16x2 habs2(f16x2 x){ U32H2 t; t.h=x; t.u&=0x7fff7fffu; return t.h; }

#if __has_builtin(__builtin_amdgcn_fdot2)
static __device__ __forceinline__ float dot2acc(f16x2 d, float acc){
    const f16x2 one = {(_Float16)1.0f, (_Float16)1.0f};
    return __builtin_amdgcn_fdot2(d, one, acc, false);
}
#else
static __device__ __forceinline__ float dot2acc(f16x2 d, float acc){ return acc + (float)d[0] + (float)d[1]; }
#endif

// 4-tap weighted sum with -cur folded into the innermost FMA
static __device__ __forceinline__ f16x2 bilin4(f16x2 ta, f16x2 tb, f16x2 tc, f16x2 td,
                                               f16x2 w00, f16x2 w01, f16x2 w10, f16x2 w11,
                                               f16x2 nc){
    f16x2 s = __builtin_elementwise_fma(td, w11, nc);
    s = __builtin_elementwise_fma(tc, w10, s);
    s = __builtin_elementwise_fma(tb, w01, s);
    s = __builtin_elementwise_fma(ta, w00, s);
    return s;
}

// butterfly add within 16-lane group via DPP (VALU pipe, no DS)
static __device__ __forceinline__ float dppadd(float x, const int ctrl){
    int p;
    switch (ctrl){
    case 0: p = __builtin_amdgcn_update_dpp(0, __float_as_int(x), 0xB1, 0xf, 0xf, true); break; // xor1
    case 1: p = __builtin_amdgcn_update_dpp(0, __float_as_int(x), 0x4E, 0xf, 0xf, true); break; // xor2
    case 2: p = __builtin_amdgcn_update_dpp(0, __float_as_int(x), 0x141, 0xf, 0xf, true); break; // xor4
    default: p = __builtin_amdgcn_update_dpp(0, __float_as_int(x), 0x140, 0xf, 0xf, true); break; // xor8
    }
    return x + __int_as_float(p);
}

__device__ __forceinline__ float depth_bin(int d){
    return (float)(0.1 + (double)d * (19.9 / 95.0));
}

// transpose + f32->f16: src [nslice][C][HW] f32 -> dst [nslice][HW][C] f16
__global__ void transpose_kernel(const float* __restrict__ src,
                                 _Float16* __restrict__ dst){
    __shared__ float tile[32][33];
    const int tx = threadIdx.x & 31, ty = threadIdx.x >> 5;
    const int nc = C_ / 32;     // 4
    const int np = HW_ / 32;    // 192
    int bid = blockIdx.x;
    int p0 = (bid % np) * 32;
    int c0 = ((bid / np) % nc) * 32;
    int s  = bid / (np * nc);
    const float* sp = src + (size_t)s * C_ * HW_;
    _Float16* dp = dst + (size_t)s * HW_ * C_;
#pragma unroll
    for (int j = 0; j < 4; ++j){
        int c = c0 + ty + j * 8;
        tile[ty + j * 8][tx] = sp[(size_t)c * HW_ + p0 + tx];
    }
    __syncthreads();
#pragma unroll
    for (int j = 0; j < 4; ++j){
        int p = p0 + ty + j * 8;
        dp[(size_t)p * C_ + c0 + tx] = (_Float16)tile[tx][ty + j * 8];
    }
}

// one wave per output pixel. 64 lanes = 4 groups x 16 lanes. Group g walks a
// CONTIGUOUS depth run: logical slot = (g>>1)*96 + (g&1)*48 + sq, sq=0..47
// (f = g>>1, d = (g&1)*48+sq). Storage layout meta[sq*4+g] keeps the 4 groups'
// broadcast ds_read_b128 conflict-free. Because the projected tap quad moves
// by ~1.5/d^2 px per depth step, most consecutive sq share the SAME quad:
// tap loads are guarded by (m.x != prevA) and tap registers retained —
// exec-masked loads fetch bytes only for groups whose quad changed (exact
// skip: same address => same data). R11 confirmed: 88.2 -> 67us.
// Config history (FINAL = R11 config):
//   (256,8)+u4: spill storm (WRITE 171MB), 131us
//   (256,4)+u4: 88.5us (R8), 67us with tap-dedup (R11)  <= BEST, kept
//   (256,6)+u2: 91us (MLP loss); (256,6)+u4: 70us + spill creep (R12)
// Occupancy is NOT the lever (R9, R12); WRITE ~19MB = no-spill signature.
__global__ __launch_bounds__(256, 4)
void cost_tr_kernel(const float* __restrict__ poses,
                    const float* __restrict__ Kmat,
                    const float* __restrict__ invKm,
                    const _Float16* __restrict__ LT,
                    const _Float16* __restrict__ CT,
                    float* __restrict__ out_cost,
                    float* __restrict__ out_missing)
{
    __shared__ __align__(16) uint4 meta[4][192];   // 12288 B, storage slot ss = sq*4+g
    __shared__ float vals[4][256];                 // logical slot f*96+d (192 real + 64 scratch)

    const int wid  = threadIdx.x >> 6;
    const int lane = threadIdx.x & 63;
    const int pg   = blockIdx.x * 4 + wid;
    const int b    = pg / HW_;
    const int pix  = pg % HW_;
    const int h    = pix / W_;
    const int w    = pix % W_;
    const size_t ob = (size_t)b * D_ * HW_ + pix;

    // border fast path: whole column is cost=0, missing=1
    if (h < 2 || h > H_-3 || w < 2 || w > W_-3){
        out_cost[ob + (size_t)lane * HW_] = 0.f;
        out_missing[ob + (size_t)lane * HW_] = 1.f;
        if (lane < 32){
            out_cost[ob + (size_t)(64+lane) * HW_] = 0.f;
            out_missing[ob + (size_t)(64+lane) * HW_] = 1.f;
        }
        return;
    }

    // ---- projection setup for both frames (wave-uniform) ----
    float Qx[2], Qy[2], Qz[2], Tx[2], Ty[2], Tz[2], Vf[2];
    {
        const float* iK = invKm + b*16;
        const float u = (float)w, v = (float)h;
        const float dirx = iK[0]*u + iK[1]*v + iK[2];
        const float diry = iK[4]*u + iK[5]*v + iK[6];
        const float dirz = iK[8]*u + iK[9]*v + iK[10];
        const float* Kb = Kmat + b*16;
#pragma unroll
        for (int f = 0; f < 2; ++f){
            const float* ps = poses + ((size_t)b*F_ + f)*16;
            float psum = 0.f;
#pragma unroll
            for (int i = 0; i < 16; ++i) psum += ps[i];
            Vf[f] = (psum != 0.f) ? 1.f : 0.f;
            float P[3][4];
#pragma unroll
            for (int i = 0; i < 3; ++i)
#pragma unroll
                for (int j = 0; j < 4; ++j)
                    P[i][j] = Kb[i*4+0]*ps[j]    + Kb[i*4+1]*ps[4+j]
                            + Kb[i*4+2]*ps[8+j]  + Kb[i*4+3]*ps[12+j];
            Qx[f] = P[0][0]*dirx + P[0][1]*diry + P[0][2]*dirz;
            Qy[f] = P[1][0]*dirx + P[1][1]*diry + P[1][2]*dirz;
            Qz[f] = P[2][0]*dirx + P[2][1]*diry + P[2][2]*dirz;
            Tx[f] = P[0][3]; Ty[f] = P[1][3]; Tz[f] = P[2][3];
        }
    }

    // ---- meta build: lane-parallel over storage slots ss = sq*4 + g ----
#pragma unroll
    for (int g3 = 0; g3 < 3; ++g3){
        int ss = g3*64 + lane;
        int g  = ss & 3;
        int sq = ss >> 2;
        int f  = g >> 1;
        int d  = (g & 1)*48 + sq;
        float dv = depth_bin(d);
        float qx = f ? Qx[1] : Qx[0];
        float qy = f ? Qy[1] : Qy[0];
        float qz = f ? Qz[1] : Qz[0];
        float tx = f ? Tx[1] : Tx[0];
        float ty = f ? Ty[1] : Ty[0];
        float tz = f ? Tz[1] : Tz[0];
        float vfl = f ? Vf[1] : Vf[0];
        float cz = qz*dv + tz + EPS_;
        float x = (qx*dv + tx) / cz;
        float y = (qy*dv + ty) / cz;
        // edge => strictly interior => no clamping/validity needed;
        // non-edge slots contribute exactly 0 (mask word in .w).
        bool edge = (x >= 2.f) && (x <= (float)(W_-2)) &&
                    (y >= 2.f) && (y <= (float)(H_-2)) && (vfl != 0.f);
        float x0f = floorf(x), y0f = floorf(y);
        float wx1 = x - x0f, wy1 = y - y0f;
        float wx0 = 1.f - wx1, wy0 = 1.f - wy1;
        float xc = fminf(fmaxf(x0f, 0.f), (float)(W_-1));
        float yc = fminf(fmaxf(y0f, 0.f), (float)(H_-1));
        int ix0 = (int)xc, iy0 = (int)yc;
        int sb = (b*F_ + f) * HW_;
        unsigned mA = (unsigned)(sb + iy0*W_ + ix0) << 8;   // clean byte address
        U32H2 t0, t1;
        t0.h[0] = (_Float16)(wy0*wx0); t0.h[1] = (_Float16)(wy0*wx1);
        t1.h[0] = (_Float16)(wy1*wx0); t1.h[1] = (_Float16)(wy1*wx1);
        meta[wid][ss] = make_uint4(mA, t0.u, t1.u, edge ? 0xffffffffu : 0u);
    }

    // ---- cur channels for this lane: (lane&15)*8 .. +8 (negated for FMA fold) ----
    const char* CTc = (const char*)CT;
    const char* LTc = (const char*)LT;
    const unsigned chanoff = (unsigned)((lane & 15) * 16);
    const int grp = lane >> 4;
    const uint4 cu = *(const uint4*)(CTc + (size_t)(b*HW_ + pix) * (C_*2) + chanoff);
    const f16x2 nc0 = -asH2(cu.x), nc1 = -asH2(cu.y), nc2 = -asH2(cu.z), nc3 = -asH2(cu.w);

    // vals write address: winner lane (lane&15)==0 writes LOGICAL slot, rest scratch
    const bool winner = ((lane & 15) == 0);
    const unsigned logbase = (unsigned)(((grp >> 1)*96 + (grp & 1)*48) * 4);
    unsigned waddr = winner ? logbase : (unsigned)((192 + lane) * 4);
    const unsigned wstep = winner ? 4u : 0u;
    char* valsbase = (char*)&vals[wid][0];

    const uint4* metabase = &meta[wid][grp];

    unsigned prevA = 0xffffffffu;          // sentinel: mA always has low 8 bits 0
    uint4 ta = make_uint4(0,0,0,0), tb = ta, tc = ta, td = ta;

#pragma unroll 4
    for (int sq = 0; sq < 48; ++sq){
        uint4 m = metabase[sq*4];          // ds_read_b128, broadcast x16
        if (m.x != prevA){                 // group-uniform; exec-masked loads
            const char* p0 = LTc + (m.x + chanoff);
            ta = *(const uint4*)(p0);
            tb = *(const uint4*)(p0 + 256);
            tc = *(const uint4*)(p0 + 256*W_);
            td = *(const uint4*)(p0 + 256*W_ + 256);
        }
        prevA = m.x;
        f16x2 hA = asH2(m.y), hB = asH2(m.z);
        f16x2 w00 = {hA[0],hA[0]}, w01 = {hA[1],hA[1]};
        f16x2 w10 = {hB[0],hB[0]}, w11 = {hB[1],hB[1]};
        f16x2 s0 = bilin4(asH2(ta.x), asH2(tb.x), asH2(tc.x), asH2(td.x), w00,w01,w10,w11, nc0);
        f16x2 s1 = bilin4(asH2(ta.y), asH2(tb.y), asH2(tc.y), asH2(td.y), w00,w01,w10,w11, nc1);
        f16x2 s2 = bilin4(asH2(ta.z), asH2(tb.z), asH2(tc.z), asH2(td.z), w00,w01,w10,w11, nc2);
        f16x2 s3 = bilin4(asH2(ta.w), asH2(tb.w), asH2(tc.w), asH2(td.w), w00,w01,w10,w11, nc3);
        float part = dot2acc(habs2(s0), 0.f);
        part = dot2acc(habs2(s1), part);
        part = dot2acc(habs2(s2), part);
        part = dot2acc(habs2(s3), part);
        part = __uint_as_float(__float_as_uint(part) & m.w);   // precomputed edge mask
        part = dppadd(part, 0);
        part = dppadd(part, 1);
        part = dppadd(part, 2);
        part = dppadd(part, 3);
        *(float*)(valsbase + waddr) = part;
        waddr += wstep;
    }

    // ---- epilogue: pair df0/df1, divide, max-fill, store (vals logical layout) ----
    float v0 = vals[wid][lane];
    float v1 = vals[wid][64 + lane];
    float v2 = vals[wid][128 + lane];
    const float invc = 1.0f / C_;

    float sent = (lane < 32) ? v2 : v1;
    float df0_1 = v0 * invc;
    float df1_1 = __shfl_xor(sent, 32) * invc;
    float cnt1 = (df0_1 > 0.f ? 1.f : 0.f) + (df1_1 > 0.f ? 1.f : 0.f);
    float val1 = (df0_1 + df1_1) / (cnt1 + EPS_);

    float df0_2 = v1 * invc;
    float df1_2 = __shfl_xor(v2, 32) * invc;
    float cnt2 = (df0_2 > 0.f ? 1.f : 0.f) + (df1_2 > 0.f ? 1.f : 0.f);
    float val2 = (df0_2 + df1_2) / (cnt2 + EPS_);

    float vmax = fmaxf(val1, (lane < 32) ? val2 : 0.f);
#pragma unroll
    for (int mm = 1; mm < 64; mm <<= 1)
        vmax = fmaxf(vmax, __shfl_xor(vmax, mm));

    {
        size_t o = ob + (size_t)lane * HW_;
        out_cost[o]    = (val1 == 0.f) ? vmax : val1;
        out_missing[o] = (val1 == 0.f) ? 1.f : 0.f;
    }
    if (lane < 32){
        size_t o = ob + (size_t)(64 + lane) * HW_;
        out_cost[o]    = (val2 == 0.f) ? vmax : val2;
        out_missing[o] = (val2 == 0.f) ? 1.f : 0.f;
    }
}

// naive correct fallback (one thread per pixel column) — only runs if ws too small
__global__ void cost_naive_kernel(const float* __restrict__ cur,
                                  const float* __restrict__ look,
                                  const float* __restrict__ poses,
                                  const float* __restrict__ Kmat,
                                  const float* __restrict__ invKm,
                                  float* __restrict__ out_cost,
                                  float* __restrict__ out_missing)
{
    int t = blockIdx.x * blockDim.x + threadIdx.x;
    if (t >= B_*HW_) return;
    int b = t / HW_, pix = t % HW_;
    int h = pix / W_, w = pix % W_;
    size_t ob = (size_t)b * D_ * HW_ + pix;
    bool border = (h >= 2 && h <= H_-3 && w >= 2 && w <= W_-3);
    const float* iK = invKm + b*16;
    float u = (float)w, v = (float)h;
    float dirx = iK[0]*u + iK[1]*v + iK[2];
    float diry = iK[4]*u + iK[5]*v + iK[6];
    float dirz = iK[8]*u + iK[9]*v + iK[10];
    const float* Kb = Kmat + b*16;
    float vmax = 0.f;
    for (int d = 0; d < D_; ++d){
        float dfs[2];
        for (int f = 0; f < 2; ++f){
            const float* ps = poses + ((size_t)b*F_ + f)*16;
            float psum = 0.f;
            for (int i = 0; i < 16; ++i) psum += ps[i];
            float vfl = (psum != 0.f) ? 1.f : 0.f;
            float P[3][4];
            for (int i = 0; i < 3; ++i)
                for (int j = 0; j < 4; ++j)
                    P[i][j] = Kb[i*4+0]*ps[j] + Kb[i*4+1]*ps[4+j]
                            + Kb[i*4+2]*ps[8+j] + Kb[i*4+3]*ps[12+j];
            float qx = P[0][0]*dirx + P[0][1]*diry + P[0][2]*dirz;
            float qy = P[1][0]*dirx + P[1][1]*diry + P[1][2]*dirz;
            float qz = P[2][0]*dirx + P[2][1]*diry + P[2][2]*dirz;
            float dv = depth_bin(d);
            float cz = qz*dv + P[2][3] + EPS_;
            float x = (qx*dv + P[0][3]) / cz;
            float y = (qy*dv + P[1][3]) / cz;
            bool edge = border && (x >= 2.f) && (x <= (float)(W_-2)) &&
                        (y >= 2.f) && (y <= (float)(H_-2)) && (vfl != 0.f);
            float part = 0.f;
            if (edge){
                float x0f = floorf(x), y0f = floorf(y);
                float wx1 = x - x0f, wy1 = y - y0f;
                float wx0 = 1.f - wx1, wy0 = 1.f - wy1;
                int ix0 = (int)x0f, iy0 = (int)y0f;
                const float* lb = look + (size_t)(b*F_+f) * C_ * HW_;
                const float* cb = cur + (size_t)b * C_ * HW_ + pix;
                int o00 = iy0*W_ + ix0;
                for (int c = 0; c < C_; ++c){
                    const float* lc = lb + (size_t)c * HW_;
                    float wv = wy0*wx0*lc[o00] + wy0*wx1*lc[o00+1]
                             + wy1*wx0*lc[o00+W_] + wy1*wx1*lc[o00+W_+1];
                    part += fabsf(wv - cb[(size_t)c * HW_]);
                }
                part *= (1.0f/C_);
            }
            dfs[f] = part;
        }
        float cnt = (dfs[0] > 0.f ? 1.f : 0.f) + (dfs[1] > 0.f ? 1.f : 0.f);
        float val = (dfs[0] + dfs[1]) / (cnt + EPS_);
        out_cost[ob + (size_t)d * HW_] = val;
        vmax = fmaxf(vmax, val);
    }
    for (int d = 0; d < D_; ++d){
        float vv = out_cost[ob + (size_t)d * HW_];
        out_missing[ob + (size_t)d * HW_] = (vv == 0.f) ? 1.f : 0.f;
        if (vv == 0.f) out_cost[ob + (size_t)d * HW_] = vmax;
    }
}

extern "C" void kernel_launch(void* const* d_in, const int* in_sizes, int n_in,
                              void* d_out, int out_size, void* d_ws, size_t ws_size,
                              hipStream_t stream){
    const float* cur   = (const float*)d_in[0];
    const float* look  = (const float*)d_in[1];
    const float* poses = (const float*)d_in[2];
    const float* Kmat  = (const float*)d_in[3];
    const float* invKm = (const float*)d_in[4];
    float* cost    = (float*)d_out;
    float* missing = cost + (size_t)B_ * D_ * HW_;

    const size_t ltBytes = (size_t)B_ * F_ * HW_ * C_ * 2;
    const size_t ctBytes = (size_t)B_ * HW_ * C_ * 2;
    const bool useTR = (ws_size >= ltBytes + ctBytes);

    if (useTR){
        _Float16* LT = (_Float16*)d_ws;
        _Float16* CT = (_Float16*)((char*)d_ws + ltBytes);
        transpose_kernel<<<(B_*F_)*(C_/32)*(HW_/32), 256, 0, stream>>>(look, LT);
        transpose_kernel<<<B_*(C_/32)*(HW_/32), 256, 0, stream>>>(cur, CT);
        cost_tr_kernel<<<(B_*HW_)/4, 256, 0, stream>>>(poses, Kmat, invKm,
                                                       LT, CT, cost, missing);
    } else {
        cost_naive_kernel<<<(B_*HW_ + 255)/256, 256, 0, stream>>>(
            cur, look, poses, Kmat, invKm, cost, missing);
    }
}